// Round 7
// baseline (113.767 us; speedup 1.0000x reference)
//
#include <hip/hip_runtime.h>
#include <hip/hip_bf16.h>

typedef __attribute__((ext_vector_type(8))) short short8;   // 8 bf16 (4 VGPRs)
typedef __attribute__((ext_vector_type(4))) float float4v;  // 4 fp32 acc

// z is pre-scaled by sqrt(2*log2(e)), so MFMA dot = 2*log2(e)*cos and
// exp(2*cos) = exp2(dot) directly — no multiply in the epilogue.
#define ZSCALE 1.6986436f

__device__ __forceinline__ float bf16lo(unsigned int u){ return __uint_as_float((u & 0xFFFFu) << 16); }
__device__ __forceinline__ float bf16hi(unsigned int u){ return __uint_as_float(u & 0xFFFF0000u); }

__device__ __forceinline__ unsigned int pack_bf16(float x, float y){
    __hip_bfloat16 h0 = __float2bfloat16(x);
    __hip_bfloat16 h1 = __float2bfloat16(y);
    unsigned short b0, b1;
    __builtin_memcpy(&b0, &h0, 2);
    __builtin_memcpy(&b1, &h1, 2);
    return (unsigned int)b0 | ((unsigned int)b1 << 16);
}

// K1 (prep): one wave per group, 4 groups per 256-block.
// Fast path (c==4, the actual workload): rows held in registers; ONE batched 6-step
// shuffle reduce for the 4 norms; bf16-round in-register; 10 unique pair-dots
// (symmetric) from registers; ONE batched 6-step reduce for all 10; lane 0 writes
// pos/self. Generic fallback for c != 4.
__global__ void k_prep(const float* __restrict__ f, const int* __restrict__ nc,
                       unsigned int* __restrict__ zb, float* __restrict__ t,
                       float* __restrict__ possum, float* __restrict__ selfs,
                       float* __restrict__ out, int G){
    int lane = threadIdx.x & 63;
    int g = blockIdx.x * 4 + (threadIdx.x >> 6);
    if (g == 0 && lane == 0) out[0] = 0.0f;
    if (g >= G) return;
    // group start = sum nc[0..g) (4-wide strided, one reduce)
    int st = 0;
    {
        int i = lane;
        for (; i + 192 < g; i += 256)
            st += nc[i] + nc[i + 64] + nc[i + 128] + nc[i + 192];
        for (; i < g; i += 64) st += nc[i];
    }
    #pragma unroll
    for (int m = 1; m < 64; m <<= 1) st += __shfl_xor(st, m);
    int c = nc[g];
    for (int i = lane; i < c; i += 64) t[st + i] = 0.0f;

    if (c == 4){
        float2 v[4]; float ss[4];
        #pragma unroll
        for (int a = 0; a < 4; a++){
            v[a] = ((const float2*)(f + (size_t)(st + a) * 128))[lane];
            ss[a] = v[a].x * v[a].x + v[a].y * v[a].y;
        }
        #pragma unroll
        for (int m = 1; m < 64; m <<= 1){
            ss[0] += __shfl_xor(ss[0], m);
            ss[1] += __shfl_xor(ss[1], m);
            ss[2] += __shfl_xor(ss[2], m);
            ss[3] += __shfl_xor(ss[3], m);
        }
        float zx[4], zy[4];
        #pragma unroll
        for (int a = 0; a < 4; a++){
            float scale = ZSCALE / fmaxf(sqrtf(ss[a]), 1e-8f);
            unsigned int pk = pack_bf16(v[a].x * scale, v[a].y * scale);
            zb[(st + a) * 64 + lane] = pk;
            zx[a] = bf16lo(pk); zy[a] = bf16hi(pk);   // the SAME values k_gram sees
        }
        // 10 unique dots: order (0,0)(0,1)(0,2)(0,3)(1,1)(1,2)(1,3)(2,2)(2,3)(3,3)
        float s[10];
        s[0] = zx[0]*zx[0] + zy[0]*zy[0];
        s[1] = zx[0]*zx[1] + zy[0]*zy[1];
        s[2] = zx[0]*zx[2] + zy[0]*zy[2];
        s[3] = zx[0]*zx[3] + zy[0]*zy[3];
        s[4] = zx[1]*zx[1] + zy[1]*zy[1];
        s[5] = zx[1]*zx[2] + zy[1]*zy[2];
        s[6] = zx[1]*zx[3] + zy[1]*zy[3];
        s[7] = zx[2]*zx[2] + zy[2]*zy[2];
        s[8] = zx[2]*zx[3] + zy[2]*zy[3];
        s[9] = zx[3]*zx[3] + zy[3]*zy[3];
        #pragma unroll
        for (int m = 1; m < 64; m <<= 1)
            #pragma unroll
            for (int u = 0; u < 10; u++) s[u] += __shfl_xor(s[u], m);
        if (lane == 0){
            float E0 = exp2f(s[0]), E1 = exp2f(s[1]), E2 = exp2f(s[2]), E3 = exp2f(s[3]);
            float E4 = exp2f(s[4]), E5 = exp2f(s[5]), E6 = exp2f(s[6]), E7 = exp2f(s[7]);
            float E8 = exp2f(s[8]), E9 = exp2f(s[9]);
            possum[st + 0] = E1 + E2 + E3;  selfs[st + 0] = E0;
            possum[st + 1] = E1 + E5 + E6;  selfs[st + 1] = E4;
            possum[st + 2] = E2 + E5 + E8;  selfs[st + 2] = E7;
            possum[st + 3] = E3 + E6 + E8;  selfs[st + 3] = E9;
        }
    } else {
        // generic fallback (any c): normalize+store, then pairwise dots via zb reload
        for (int r = 0; r < c; r++){
            const float2* fr = (const float2*)(f + (size_t)(st + r) * 128);
            float2 vv = fr[lane];
            float ss2 = vv.x * vv.x + vv.y * vv.y;
            #pragma unroll
            for (int m = 1; m < 64; m <<= 1) ss2 += __shfl_xor(ss2, m);
            float scale = ZSCALE / fmaxf(sqrtf(ss2), 1e-8f);
            zb[(st + r) * 64 + lane] = pack_bf16(vv.x * scale, vv.y * scale);
        }
        for (int a = 0; a < c; a++){
            unsigned int ua = zb[(st + a) * 64 + lane];
            float a0 = bf16lo(ua), a1 = bf16hi(ua);
            float pacc = 0.0f;
            for (int b = 0; b < c; b++){
                unsigned int ub = zb[(st + b) * 64 + lane];
                float sdot = a0 * bf16lo(ub) + a1 * bf16hi(ub);
                #pragma unroll
                for (int m = 1; m < 64; m <<= 1) sdot += __shfl_xor(sdot, m);
                float e = exp2f(sdot);
                if (b == a){ if (lane == 0) selfs[st + a] = e; }
                else pacc += e;
            }
            if (lane == 0) possum[st + a] = pacc;
        }
    }
}

// K2: barrier-free Gram row-sums (R5 structure — best measured), strip loop
// unrolled x2 with both strips' 8 loads batched up front (2x memory-level
// parallelism; uses follow in-iteration so the compiler can't sink them).
// Grid (N/256, N/256); block = 4 independent waves; wave = 64 rows x 256 cols,
// processed as 8 iterations of two 16-col strips.
// Fragment: lane holds z[base+(lane&15)][ki*32 + (lane>>4)*8 .. +7]
// C layout: col = lane&15, row_local = mi*16 + quad*4 + r.
__global__ __launch_bounds__(256) void k_gram(const unsigned short* __restrict__ z,
                                              float* __restrict__ t, int N){
    int tid  = threadIdx.x;
    int lane = tid & 63, w = tid >> 6;
    int quad = lane >> 4, l15 = lane & 15;
    int r0 = blockIdx.x * 256 + w * 64;
    int c0 = blockIdx.y * 256;
    size_t lq = (size_t)l15 * 128 + quad * 8;

    const unsigned short* za = z + (size_t)r0 * 128;
    short8 af[4][4];
    #pragma unroll
    for (int mi = 0; mi < 4; mi++)
        #pragma unroll
        for (int ki = 0; ki < 4; ki++)
            af[mi][ki] = *(const short8*)&za[(size_t)(mi * 16) * 128 + lq + ki * 32];

    float ts[4][4];
    #pragma unroll
    for (int mi = 0; mi < 4; mi++)
        #pragma unroll
        for (int r = 0; r < 4; r++) ts[mi][r] = 0.0f;

    const unsigned short* zp = z + (size_t)c0 * 128 + lq;
    #pragma unroll 1
    for (int it = 0; it < 8; it++){
        // both strips' loads issued together (8 x 16B in flight)
        short8 b0 = *(const short8*)(zp);
        short8 b1 = *(const short8*)(zp + 32);
        short8 b2 = *(const short8*)(zp + 64);
        short8 b3 = *(const short8*)(zp + 96);
        short8 c0v = *(const short8*)(zp + 2048);
        short8 c1v = *(const short8*)(zp + 2048 + 32);
        short8 c2v = *(const short8*)(zp + 2048 + 64);
        short8 c3v = *(const short8*)(zp + 2048 + 96);

        float4v acc[4];
        #pragma unroll
        for (int mi = 0; mi < 4; mi++) acc[mi] = (float4v){0.0f, 0.0f, 0.0f, 0.0f};
        #pragma unroll
        for (int mi = 0; mi < 4; mi++)
            acc[mi] = __builtin_amdgcn_mfma_f32_16x16x32_bf16(af[mi][0], b0, acc[mi], 0, 0, 0);
        #pragma unroll
        for (int mi = 0; mi < 4; mi++)
            acc[mi] = __builtin_amdgcn_mfma_f32_16x16x32_bf16(af[mi][1], b1, acc[mi], 0, 0, 0);
        #pragma unroll
        for (int mi = 0; mi < 4; mi++)
            acc[mi] = __builtin_amdgcn_mfma_f32_16x16x32_bf16(af[mi][2], b2, acc[mi], 0, 0, 0);
        #pragma unroll
        for (int mi = 0; mi < 4; mi++)
            acc[mi] = __builtin_amdgcn_mfma_f32_16x16x32_bf16(af[mi][3], b3, acc[mi], 0, 0, 0);
        #pragma unroll
        for (int mi = 0; mi < 4; mi++)
            #pragma unroll
            for (int r = 0; r < 4; r++)
                ts[mi][r] += exp2f(acc[mi][r]);

        float4v acc2[4];
        #pragma unroll
        for (int mi = 0; mi < 4; mi++) acc2[mi] = (float4v){0.0f, 0.0f, 0.0f, 0.0f};
        #pragma unroll
        for (int mi = 0; mi < 4; mi++)
            acc2[mi] = __builtin_amdgcn_mfma_f32_16x16x32_bf16(af[mi][0], c0v, acc2[mi], 0, 0, 0);
        #pragma unroll
        for (int mi = 0; mi < 4; mi++)
            acc2[mi] = __builtin_amdgcn_mfma_f32_16x16x32_bf16(af[mi][1], c1v, acc2[mi], 0, 0, 0);
        #pragma unroll
        for (int mi = 0; mi < 4; mi++)
            acc2[mi] = __builtin_amdgcn_mfma_f32_16x16x32_bf16(af[mi][2], c2v, acc2[mi], 0, 0, 0);
        #pragma unroll
        for (int mi = 0; mi < 4; mi++)
            acc2[mi] = __builtin_amdgcn_mfma_f32_16x16x32_bf16(af[mi][3], c3v, acc2[mi], 0, 0, 0);
        #pragma unroll
        for (int mi = 0; mi < 4; mi++)
            #pragma unroll
            for (int r = 0; r < 4; r++)
                ts[mi][r] += exp2f(acc2[mi][r]);

        zp += 32 * 128;   // two 16-col strips
    }

    // reduce across the 16 column-lanes (same quad), one atomic per row
    #pragma unroll
    for (int mi = 0; mi < 4; mi++)
        #pragma unroll
        for (int r = 0; r < 4; r++){
            float v = ts[mi][r];
            v += __shfl_xor(v, 1);
            v += __shfl_xor(v, 2);
            v += __shfl_xor(v, 4);
            v += __shfl_xor(v, 8);
            if (l15 == 0) atomicAdd(&t[r0 + mi * 16 + quad * 4 + r], v);
        }
}

// K3: loss = mean over rows of log(neg) - log(pos); neg = t - pos - self.
__global__ void k_final(const float* __restrict__ t, const float* __restrict__ possum,
                        const float* __restrict__ selfs, float* __restrict__ out, int N){
    int tid = threadIdx.x;
    int gid = blockIdx.x * 256 + tid;
    float s = 0.0f;
    if (gid < N){
        float p = possum[gid];
        float n = t[gid] - p - selfs[gid];
        s = logf(n) - logf(p);
    }
    #pragma unroll
    for (int m = 1; m < 64; m <<= 1) s += __shfl_xor(s, m);
    __shared__ float red[4];
    if ((tid & 63) == 0) red[tid >> 6] = s;
    __syncthreads();
    if (tid == 0) atomicAdd(out, (red[0] + red[1] + red[2] + red[3]) / (float)N);
}

extern "C" void kernel_launch(void* const* d_in, const int* in_sizes, int n_in,
                              void* d_out, int out_size, void* d_ws, size_t ws_size,
                              hipStream_t stream){
    const float* f  = (const float*)d_in[0];
    const int*   nc = (const int*)d_in[1];
    int N = in_sizes[0] / 128;   // 8192
    int G = in_sizes[1];         // 2048

    unsigned int* zb = (unsigned int*)d_ws;                       // N*256 B bf16 z (pre-scaled)
    float* t     = (float*)((char*)d_ws + (size_t)N * 256);       // N fp32
    float* pos   = t + N;
    float* selfs = pos + N;
    float* out   = (float*)d_out;

    k_prep<<<(G + 3) / 4, 256, 0, stream>>>(f, nc, zb, t, pos, selfs, out, G);
    dim3 grid(N / 256, N / 256);
    k_gram<<<grid, 256, 0, stream>>>((const unsigned short*)zb, t, N);
    k_final<<<(N + 255) / 256, 256, 0, stream>>>(t, pos, selfs, out, N);
}